// Round 14
// baseline (217.442 us; speedup 1.0000x reference)
//
#include <hip/hip_runtime.h>
#include <hip/hip_bf16.h>

typedef __attribute__((ext_vector_type(8))) short short8;
typedef __attribute__((ext_vector_type(16))) float float16v;
typedef __attribute__((ext_vector_type(4))) int int4v;
typedef __attribute__((ext_vector_type(2))) int int2v;
typedef _Float16 half4v __attribute__((ext_vector_type(4)));

#define NB 32
#define LL 128
#define DDIM 300
#define DP 320
#define KDIM 50
#define WTILE_E 10240            // elems per (k, et) wtile: 32 rows x 320
#define WBT_K   102400           // elems per k (10 tiles)
#define E2TILE_E 4096            // elems per (b, et) e2 tile: 4 granules x 128 j x 8
#define SLAB_OFF 18759680ull
#define SLAB_BYTES (50ull * 32ull * 16384ull * 2ull)          // 52,428,800
#define WS_NEED  (SLAB_OFF + SLAB_BYTES)

__device__ __forceinline__ unsigned short f2bf(float x) {
    unsigned int u = __float_as_uint(x);
    unsigned int r = (u + 0x7FFFu + ((u >> 16) & 1u)) >> 16;
    return (unsigned short)r;
}
__device__ __forceinline__ float16v mfma32(short8 a, short8 b, float16v c) {
    return __builtin_amdgcn_mfma_f32_32x32x16_bf16(a, b, c, 0, 0, 0);
}
__device__ __forceinline__ unsigned int cvtpk(float lo, float hi) {
    unsigned int r;
    asm("v_cvt_pk_bf16_f32 %0, %1, %2" : "=v"(r) : "v"(lo), "v"(hi));
    return r;
}
__device__ __forceinline__ void gload_lds16(const void* g, void* l) {
    __builtin_amdgcn_global_load_lds((const __attribute__((address_space(1))) void*)g,
                                     (__attribute__((address_space(3))) void*)l, 16, 0, 0);
}

// ---------- fused prep: [0,1000) Wb->Wbt arm; [1000,1512) projections+convert arm ----------
// R14 = R6-exact (verified best total 208.55us). All later prep experiments
// (wave-split R11/R12: +35us; 2x row-split R10: +38us; unroll-2 R13: null)
// reverted. Wbt layout (XOR-swizzled for grn's global_load_lds staging):
//   elem offset = k*102400 + et*10240 + (e&31)*320 + (d ^ ((e&7)<<3))
// Transpose arm: writer gathers 8 consecutive d down an LDS column
// (stride-33, conflict-free) and emits ONE short8 store. 1000 blocks.
// e2til layout: per (b, et) linear 8192B tile, granule-major:
//   elem ((b*10+et)*4 + g)*1024 + j*8 + jj
__global__ void prep_all(const float* __restrict__ e1, const float* __restrict__ e2,
                         const float* __restrict__ Wb,
                         const float* __restrict__ Wd, const float* __restrict__ Wg,
                         unsigned short* __restrict__ e1b, unsigned short* __restrict__ e2til,
                         unsigned short* __restrict__ wbt,
                         float* __restrict__ p1d, float* __restrict__ p1g,
                         float* __restrict__ p2d, float* __restrict__ p2g) {
    const int blk = blockIdx.x;
    __shared__ float tile[32][33];

    if (blk < 1000) {
        // ---- Wb transpose arm: (k, et, dt-half); 5 dt rounds ----
        int k = blk / 20, sub = blk % 20, et = sub >> 1, dh = sub & 1;
        int tx = threadIdx.x & 31, ty = threadIdx.x >> 5;
        const size_t obase = (size_t)k * WBT_K + (size_t)et * WTILE_E;
        for (int dt = dh * 5; dt < dh * 5 + 5; ++dt) {
#pragma unroll
            for (int rr = 0; rr < 4; ++rr) {
                int d = dt * 32 + ty + rr * 8;
                int e = et * 32 + tx;
                tile[ty + rr * 8][tx] = (d < DDIM && e < DDIM) ? Wb[((size_t)k * DDIM + d) * DDIM + e] : 0.f;
            }
            __syncthreads();
            if (threadIdx.x < 128) {
                int e_loc = threadIdx.x & 31, oct = threadIdx.x >> 5;   // oct 0..3
                int e7 = e_loc & 7;
                unsigned short tmp[8];
#pragma unroll
                for (int s = 0; s < 8; ++s)
                    tmp[s] = f2bf(tile[oct * 8 + s][e_loc]);
                int d0g = dt * 32 + oct * 8;
                size_t off = obase + (size_t)e_loc * 320 + (size_t)(d0g ^ (e7 << 3));
                *(short8*)&wbt[off] = *(short8*)tmp;
            }
            __syncthreads();
        }
        return;
    }
    // ---- projection + conversion arm: 512 blocks, 16 rows each ----
    int bid = blk - 1000;
    const int kk = threadIdx.x & 63;
    const int grp = threadIdx.x >> 6;
    const int kks = kk < KDIM ? kk : 0;
    const float* src; int woff; float *dd, *dg; int r0;
    int ise2;
    int rowbase = bid * 16;
    if (rowbase < 4096) { r0 = rowbase; src = e1; woff = 0; dd = p1d; dg = p1g; ise2 = 0; }
    else { r0 = rowbase - 4096; src = e2; woff = DDIM; dd = p2d; dg = p2g; ise2 = 1; }
    const float* e0 = src + (size_t)(r0 + grp * 4) * DDIM;
    const float* wdp = Wd + (size_t)woff * KDIM + kks;
    const float* wgp = Wg + (size_t)woff * KDIM + kks;

    float ad[4] = {0.f, 0.f, 0.f, 0.f}, ag[4] = {0.f, 0.f, 0.f, 0.f};
    for (int c = 0; c < DDIM / 4; ++c) {
        const int d0 = c * 4;
        float4 x[4];
#pragma unroll
        for (int rr = 0; rr < 4; ++rr)
            x[rr] = *(const float4*)(e0 + (size_t)rr * DDIM + d0);
        float wd0 = wdp[(size_t)(d0 + 0) * KDIM];
        float wd1 = wdp[(size_t)(d0 + 1) * KDIM];
        float wd2 = wdp[(size_t)(d0 + 2) * KDIM];
        float wd3 = wdp[(size_t)(d0 + 3) * KDIM];
        float wg0 = wgp[(size_t)(d0 + 0) * KDIM];
        float wg1 = wgp[(size_t)(d0 + 1) * KDIM];
        float wg2 = wgp[(size_t)(d0 + 2) * KDIM];
        float wg3 = wgp[(size_t)(d0 + 3) * KDIM];
#pragma unroll
        for (int rr = 0; rr < 4; ++rr) {
            ad[rr] += x[rr].x * wd0 + x[rr].y * wd1 + x[rr].z * wd2 + x[rr].w * wd3;
            ag[rr] += x[rr].x * wg0 + x[rr].y * wg1 + x[rr].z * wg2 + x[rr].w * wg3;
        }
    }
    if (kk < KDIM) {
#pragma unroll
        for (int rr = 0; rr < 4; ++rr) {
            size_t o = (size_t)(r0 + grp * 4 + rr) * KDIM + kk;
            dd[o] = ad[rr];
            dg[o] = ag[rr];
        }
    }
    // conversion: this block's 16 rows -> bf16 (640 granules of 8)
    for (int it = 0; it < 3; ++it) {
        int g = threadIdx.x + it * 256;
        if (g >= 640) break;
        int rl = g / 40, d0 = (g % 40) * 8;
        const float* sp = src + (size_t)(r0 + rl) * DDIM;
        float v[8];
        if (d0 + 8 <= DDIM) {
            float4 lo = *(const float4*)(sp + d0);
            float4 hi = *(const float4*)(sp + d0 + 4);
            v[0] = lo.x; v[1] = lo.y; v[2] = lo.z; v[3] = lo.w;
            v[4] = hi.x; v[5] = hi.y; v[6] = hi.z; v[7] = hi.w;
        } else if (d0 < DDIM) {          // d0 == 296
            float4 lo = *(const float4*)(sp + d0);
            v[0] = lo.x; v[1] = lo.y; v[2] = lo.z; v[3] = lo.w;
            v[4] = v[5] = v[6] = v[7] = 0.f;
        } else {
            for (int j = 0; j < 8; ++j) v[j] = 0.f;
        }
        unsigned short tmp[8];
#pragma unroll
        for (int j = 0; j < 8; ++j) tmp[j] = f2bf(v[j]);
        unsigned short* dp;
        int row = r0 + rl;
        if (!ise2) {
            dp = e1b + (size_t)row * DP + d0;                      // row-major padded
        } else {
            int bb2 = row >> 7, j = row & 127;
            int g8 = d0 >> 3, et = g8 >> 2, gg = g8 & 3;
            dp = e2til + (((size_t)(bb2 * 10 + et) * 4 + gg) * 128 + j) * 8;
        }
        *(short8*)dp = *(short8*)tmp;
    }
}

// ---------- main: per (b,k): S = (e1 Wb[k]) e2^T, gate ----------
// R6-exact (verified 94.9-96.2us across 4 runs): counted-vmcnt pipeline
// (T3/T4): wtile 3-deep (60KB), e2s 2-deep; iter n issues e2s(n+1) THEN
// wtile(n+2); barrier is raw s_barrier with s_waitcnt vmcnt(5) -- wtile(n+2)'s
// 5 loads stay in flight across it. No setprio (R8: T5 null on this
// barrier-lockstep structure). R9 lesson: do NOT remove the LDS stage -- it
// IS the latency-hiding mechanism (direct-global fragments = 2x slower).
template <int SLAB>
__global__ __launch_bounds__(256, 2) void grn_main(
    const unsigned short* __restrict__ e1b, const unsigned short* __restrict__ e2til,
    const unsigned short* __restrict__ wbt,
    const float* __restrict__ p1d, const float* __restrict__ p1g,
    const float* __restrict__ p2d, const float* __restrict__ p2g,
    const float* __restrict__ bg, const float* __restrict__ bb,
    const float* __restrict__ u, float* __restrict__ out, _Float16* __restrict__ slab) {
    const int b = blockIdx.x, k = blockIdx.y;
    const int tid = threadIdx.x;
    const int wid = tid >> 6, lane = tid & 63;
    const int l32 = lane & 31, hi = lane >> 5;
    const int rw0 = wid * 32;                      // wave owns i-rows [rw0, rw0+32)

    __shared__ __align__(16) unsigned short wtile[3][WTILE_E];   // 3 x 20480B
    __shared__ __align__(16) unsigned short e2s[2][E2TILE_E];    // 2 x 8192B
    __shared__ float pbuf[4][128];

    const unsigned short* wsrc = wbt + (size_t)k * WBT_K;
    const unsigned short* esrc = e2til + (size_t)b * (10 * E2TILE_E);

    // prologue stage: e2s(0), wtile(0) first (oldest -> drained by vmcnt(5))
#pragma unroll
    for (int it = 0; it < 2; ++it) {
        int c = wid * 2 + it;
        gload_lds16(esrc + c * 512 + lane * 8, &e2s[0][c * 512]);
    }
#pragma unroll
    for (int it = 0; it < 5; ++it) {
        int c = wid * 5 + it;
        gload_lds16(wsrc + c * 512 + lane * 8, &wtile[0][c * 512]);
    }

    if (tid < 128) {
        int gi = (b * LL + tid) * KDIM + k;
        pbuf[0][tid] = p1d[gi];
        pbuf[1][tid] = p1g[gi];
        pbuf[2][tid] = p2d[gi];
        pbuf[3][tid] = p2g[gi];
    }
    const float u_k = u[k], bg_k = bg[k], b_k = bb[k];

    // e1 B-fragments (phase1): lane holds e1[i=rw0+l32][d=c*16+hi*8+j], c=0..19
    short8 af[20];
    {
        const unsigned short* p = e1b + ((size_t)(b * LL + rw0 + l32)) * DP + hi * 8;
#pragma unroll
        for (int c = 0; c < 20; ++c)
            af[c] = *(const short8*)(p + c * 16);
    }

    float16v S[4];
#pragma unroll
    for (int jt = 0; jt < 4; ++jt)
#pragma unroll
        for (int z = 0; z < 16; ++z) S[jt][z] = 0.f;

    const int swz = (l32 & 7) << 3;                 // phase1 read swizzle (elems)
    const int ebo = hi * 1024 + l32 * 8;            // e2s frag base (elems)

    // prologue stage: wtile(1) LAST (the 5 loads vmcnt(5) leaves in flight)
    __builtin_amdgcn_sched_barrier(0);
#pragma unroll
    for (int it = 0; it < 5; ++it) {
        int c = wid * 5 + it;
        gload_lds16(wsrc + WTILE_E + c * 512 + lane * 8, &wtile[1][c * 512]);
    }
    asm volatile("s_waitcnt vmcnt(5)" ::: "memory");
    __builtin_amdgcn_s_barrier();
    __builtin_amdgcn_sched_barrier(0);

#pragma unroll
    for (int et = 0; et < 10; ++et) {
        const int wr = et % 3;                     // literal (unrolled)
        const int er = et & 1;
        // ks0 B-frags from LDS (current slot)
        short8 b0[4];
#pragma unroll
        for (int jt = 0; jt < 4; ++jt)
            b0[jt] = *(const short8*)&e2s[er][ebo + jt * 256];

        // stage e2s(et+1) FIRST, then wtile(et+2): vmcnt(5) leaves only the
        // wtile(et+2) loads outstanding across the barrier.
        if (et < 9) {
            const unsigned short* es = esrc + (et + 1) * E2TILE_E;
            unsigned short* el = &e2s[er ^ 1][0];
#pragma unroll
            for (int it = 0; it < 2; ++it) {
                int c = wid * 2 + it;
                gload_lds16(es + c * 512 + lane * 8, el + c * 512);
            }
        }
        __builtin_amdgcn_sched_barrier(0);          // pin e2s-before-wtile order
        if (et < 8) {
            const unsigned short* ws = wsrc + (et + 2) * WTILE_E;
            unsigned short* wl = &wtile[(et + 2) % 3][0];
#pragma unroll
            for (int it = 0; it < 5; ++it) {
                int c = wid * 5 + it;
                gload_lds16(ws + c * 512 + lane * 8, wl + c * 512);
            }
        }

        // phase 1 (mfma32): C[m=e'][n=i] = sum_d Wb[e'][d]*e1[i][d]
        const unsigned short* wt = &wtile[wr][l32 * 320];
        float16v t0, t1;
#pragma unroll
        for (int z = 0; z < 16; ++z) { t0[z] = 0.f; t1[z] = 0.f; }
#pragma unroll
        for (int c = 0; c < 20; c += 2) {
            short8 wa0 = *(const short8*)(wt + ((c * 16 + hi * 8) ^ swz));
            short8 wa1 = *(const short8*)(wt + (((c + 1) * 16 + hi * 8) ^ swz));
            t0 = mfma32(wa0, af[c], t0);
            t1 = mfma32(wa1, af[c + 1], t1);
        }
        // ks1 B-frags (LDS; cover = pack/swap + ks0 MFMAs)
        short8 b1[4];
#pragma unroll
        for (int jt = 0; jt < 4; ++jt)
            b1[jt] = *(const short8*)&e2s[er][ebo + 2048 + jt * 256];

        float16v tt = t0 + t1;
        // pack to bf16 pairs; lane (l32,hi) holds T[i=l32][e'=(r&3)+8*(r>>2)+4*hi]
        unsigned int P0 = cvtpk(tt[0], tt[1]);
        unsigned int P1 = cvtpk(tt[2], tt[3]);
        unsigned int P2 = cvtpk(tt[4], tt[5]);
        unsigned int P3 = cvtpk(tt[6], tt[7]);
        unsigned int P4 = cvtpk(tt[8], tt[9]);
        unsigned int P5 = cvtpk(tt[10], tt[11]);
        unsigned int P6 = cvtpk(tt[12], tt[13]);
        unsigned int P7 = cvtpk(tt[14], tt[15]);
        // half-wave exchange: dst'={dst_lo,src_lo}, src'={dst_hi,src_hi}
        int2v r02 = __builtin_amdgcn_permlane32_swap((int)P0, (int)P2, false, false);
        int2v r13 = __builtin_amdgcn_permlane32_swap((int)P1, (int)P3, false, false);
        int2v r46 = __builtin_amdgcn_permlane32_swap((int)P4, (int)P6, false, false);
        int2v r57 = __builtin_amdgcn_permlane32_swap((int)P5, (int)P7, false, false);
        short8 A0 = __builtin_bit_cast(short8, (int4v){r02[0], r13[0], r02[1], r13[1]});
        short8 A1 = __builtin_bit_cast(short8, (int4v){r46[0], r57[0], r46[1], r57[1]});
        // phase 2 (mfma32): S[i][j] += sum_e' T[i][e'] * e2[j][e']
#pragma unroll
        for (int jt = 0; jt < 4; ++jt)
            S[jt] = mfma32(A0, b0[jt], S[jt]);
#pragma unroll
        for (int jt = 0; jt < 4; ++jt)
            S[jt] = mfma32(A1, b1[jt], S[jt]);

        // counted-vmcnt barrier: wtile(et+2) stays in flight (T4).
        if (et < 8) {
            asm volatile("s_waitcnt vmcnt(5)" ::: "memory");
        } else if (et == 8) {
            asm volatile("s_waitcnt vmcnt(0)" ::: "memory");
        }
        if (et < 9) {
            __builtin_amdgcn_s_barrier();
            __builtin_amdgcn_sched_barrier(0);
        }
    }

    // epilogue: gate, mix, scale by u[k]
    // S[jt][r]: i = rw0 + (r&3)+8*(r>>2)+4*hi, j = jt*32 + l32
    float pdj[4], pgj[4];
#pragma unroll
    for (int jt = 0; jt < 4; ++jt) {
        pdj[jt] = pbuf[2][jt * 32 + l32];
        pgj[jt] = pbuf[3][jt * 32 + l32] + bg_k;
    }
    _Float16* sdst = slab + ((size_t)k * NB + b) * 16384;
    float* adst = out + (size_t)b * LL * LL;
#pragma unroll
    for (int r = 0; r < 16; ++r) {
        int i = rw0 + (r & 3) + 8 * (r >> 2) + 4 * hi;
        float pdi_ = pbuf[0][i];
        float pgi_ = pbuf[1][i];
#pragma unroll
        for (int jt = 0; jt < 4; ++jt) {
            float btp = S[jt][r];
            float sd = pdi_ + pdj[jt];
            float sg = pgi_ + pgj[jt];
            float e2x = __expf(2.f * sd);
            float sln = 1.f - 2.f * __builtin_amdgcn_rcpf(e2x + 1.f);   // tanh(sd)
            float g = __builtin_amdgcn_rcpf(1.f + __expf(-sg));          // sigmoid(sg)
            float val = u_k * (g * btp + (1.f - g) * sln + b_k);
            if (SLAB) {
                // permuted coalesced layout: pos = v*256 + tid, v = jt*16 + r
                sdst[(jt * 16 + r) * 256 + tid] = (_Float16)val;
            } else {
                unsafeAtomicAdd(adst + (size_t)i * LL + (jt * 32 + l32), val);
            }
        }
    }
}

// ---------- reduce: out[b][i][j] = sum_k slab[k][b][pos]; decode permutation ----------
__global__ void reduce_k(const _Float16* __restrict__ slab, float* __restrict__ out) {
    int idx = blockIdx.x * 256 + threadIdx.x;     // 0..131071
    int b = idx >> 12;
    int p4 = idx & 4095;
    int pos0 = p4 * 4;
    int v = pos0 >> 8, tid0 = pos0 & 255;
    int jt = v >> 4, r = v & 15;
    int wid = tid0 >> 6, lane = tid0 & 63, hi2 = lane >> 5, l32 = lane & 31;
    int i = wid * 32 + (r & 3) + 8 * (r >> 2) + 4 * hi2;
    int j0 = jt * 32 + l32;

    float a0 = 0.f, a1 = 0.f, a2 = 0.f, a3 = 0.f;
    const _Float16* sp = slab + (size_t)b * 16384 + pos0;
#pragma unroll
    for (int k = 0; k < KDIM; ++k) {
        half4v h = *(const half4v*)(sp + (size_t)k * (NB * 16384));
        a0 += (float)h[0]; a1 += (float)h[1]; a2 += (float)h[2]; a3 += (float)h[3];
    }
    float4 rv; rv.x = a0; rv.y = a1; rv.z = a2; rv.w = a3;
    *(float4*)(out + (size_t)b * 16384 + i * 128 + j0) = rv;
}

extern "C" void kernel_launch(void* const* d_in, const int* in_sizes, int n_in,
                              void* d_out, int out_size, void* d_ws, size_t ws_size,
                              hipStream_t stream) {
    const float* e1 = (const float*)d_in[0];   // (32,128,300)
    const float* e2 = (const float*)d_in[1];   // (32,128,300)
    const float* Wb = (const float*)d_in[2];   // (50,300,300)
    const float* Wd = (const float*)d_in[3];   // (600,50)
    const float* Wg = (const float*)d_in[4];   // (600,50)
    const float* bg = (const float*)d_in[5];   // (50,)
    const float* bb = (const float*)d_in[6];   // (50,)
    const float* u  = (const float*)d_in[7];   // (50,1)
    float* out = (float*)d_out;                // (32,128,128,1)

    unsigned short* e1b   = (unsigned short*)d_ws;               // 1,310,720 elems
    unsigned short* e2til = e1b + 1310720;                       // 1,310,720 elems (tiled)
    unsigned short* wbt   = e2til + 1310720;                     // 5,120,000 elems
    float* pf  = (float*)((char*)d_ws + 15482880);
    float* p1d = pf;
    float* p1g = pf + 204800;
    float* p2d = pf + 409600;
    float* p2g = pf + 614400;                                    // end 18,759,680 B
    _Float16* slab = (_Float16*)((char*)d_ws + SLAB_OFF);        // 50x32x16384 halves

    prep_all<<<1512, 256, 0, stream>>>(e1, e2, Wb, Wd, Wg,
                                       e1b, e2til, wbt,
                                       p1d, p1g, p2d, p2g);

    if (ws_size >= WS_NEED) {
        grn_main<1><<<dim3(NB, KDIM), 256, 0, stream>>>(e1b, e2til, wbt,
                                                        p1d, p1g, p2d, p2g,
                                                        bg, bb, u, out, slab);
        reduce_k<<<512, 256, 0, stream>>>(slab, out);
    } else {
        hipMemsetAsync(d_out, 0, (size_t)out_size * sizeof(float), stream);
        grn_main<0><<<dim3(NB, KDIM), 256, 0, stream>>>(e1b, e2til, wbt,
                                                        p1d, p1g, p2d, p2g,
                                                        bg, bb, u, out, slab);
    }
}

// Round 15
// 216.523 us; speedup vs baseline: 1.0042x; 1.0042x over previous
//
#include <hip/hip_runtime.h>
#include <hip/hip_bf16.h>

typedef __attribute__((ext_vector_type(8))) short short8;
typedef __attribute__((ext_vector_type(16))) float float16v;
typedef __attribute__((ext_vector_type(4))) int int4v;
typedef __attribute__((ext_vector_type(2))) int int2v;
typedef _Float16 half4v __attribute__((ext_vector_type(4)));

#define NB 32
#define LL 128
#define DDIM 300
#define DP 320
#define KDIM 50
#define WTILE_E 10240            // elems per (k, et) wtile: 32 rows x 320
#define WBT_K   102400           // elems per k (10 tiles)
#define E2TILE_E 4096            // elems per (b, et) e2 tile: 4 granules x 128 j x 8
#define SLAB_OFF 18759680ull
#define SLAB_BYTES (50ull * 32ull * 16384ull * 2ull)          // 52,428,800
#define WS_NEED  (SLAB_OFF + SLAB_BYTES)

__device__ __forceinline__ unsigned short f2bf(float x) {
    unsigned int u = __float_as_uint(x);
    unsigned int r = (u + 0x7FFFu + ((u >> 16) & 1u)) >> 16;
    return (unsigned short)r;
}
__device__ __forceinline__ float16v mfma32(short8 a, short8 b, float16v c) {
    return __builtin_amdgcn_mfma_f32_32x32x16_bf16(a, b, c, 0, 0, 0);
}
__device__ __forceinline__ unsigned int cvtpk(float lo, float hi) {
    unsigned int r;
    asm("v_cvt_pk_bf16_f32 %0, %1, %2" : "=v"(r) : "v"(lo), "v"(hi));
    return r;
}
__device__ __forceinline__ void gload_lds16(const void* g, void* l) {
    __builtin_amdgcn_global_load_lds((const __attribute__((address_space(1))) void*)g,
                                     (__attribute__((address_space(3))) void*)l, 16, 0, 0);
}

// ---------- fused prep: [0,512) projections+convert arm; [512,1512) Wb->Wbt arm ----------
// R15: ARM ORDER SWAPPED (only change vs R6-exact/R14). The 512 projection
// blocks are the long pole (75-iter load chain, ~2-3x a transpose block);
// hardware dispatches low blockIdx first, so placing them at [0,512) starts
// the long pole at t=0 with the 1000 short transpose blocks back-filling --
// removes the ~15-25us queue delay the projection wavefront previously paid.
// Pure block-index remap: identical work, addresses, and layouts.
// Wbt layout (XOR-swizzled for grn's global_load_lds staging):
//   elem offset = k*102400 + et*10240 + (e&31)*320 + (d ^ ((e&7)<<3))
// e2til layout: per (b, et) linear 8192B tile, granule-major:
//   elem ((b*10+et)*4 + g)*1024 + j*8 + jj
__global__ void prep_all(const float* __restrict__ e1, const float* __restrict__ e2,
                         const float* __restrict__ Wb,
                         const float* __restrict__ Wd, const float* __restrict__ Wg,
                         unsigned short* __restrict__ e1b, unsigned short* __restrict__ e2til,
                         unsigned short* __restrict__ wbt,
                         float* __restrict__ p1d, float* __restrict__ p1g,
                         float* __restrict__ p2d, float* __restrict__ p2g) {
    const int blk = blockIdx.x;
    __shared__ float tile[32][33];

    if (blk >= 512) {
        // ---- Wb transpose arm: (k, et, dt-half); 5 dt rounds ----
        int tb = blk - 512;
        int k = tb / 20, sub = tb % 20, et = sub >> 1, dh = sub & 1;
        int tx = threadIdx.x & 31, ty = threadIdx.x >> 5;
        const size_t obase = (size_t)k * WBT_K + (size_t)et * WTILE_E;
        for (int dt = dh * 5; dt < dh * 5 + 5; ++dt) {
#pragma unroll
            for (int rr = 0; rr < 4; ++rr) {
                int d = dt * 32 + ty + rr * 8;
                int e = et * 32 + tx;
                tile[ty + rr * 8][tx] = (d < DDIM && e < DDIM) ? Wb[((size_t)k * DDIM + d) * DDIM + e] : 0.f;
            }
            __syncthreads();
            if (threadIdx.x < 128) {
                int e_loc = threadIdx.x & 31, oct = threadIdx.x >> 5;   // oct 0..3
                int e7 = e_loc & 7;
                unsigned short tmp[8];
#pragma unroll
                for (int s = 0; s < 8; ++s)
                    tmp[s] = f2bf(tile[oct * 8 + s][e_loc]);
                int d0g = dt * 32 + oct * 8;
                size_t off = obase + (size_t)e_loc * 320 + (size_t)(d0g ^ (e7 << 3));
                *(short8*)&wbt[off] = *(short8*)tmp;
            }
            __syncthreads();
        }
        return;
    }
    // ---- projection + conversion arm: 512 blocks, 16 rows each ----
    int bid = blk;
    const int kk = threadIdx.x & 63;
    const int grp = threadIdx.x >> 6;
    const int kks = kk < KDIM ? kk : 0;
    const float* src; int woff; float *dd, *dg; int r0;
    int ise2;
    int rowbase = bid * 16;
    if (rowbase < 4096) { r0 = rowbase; src = e1; woff = 0; dd = p1d; dg = p1g; ise2 = 0; }
    else { r0 = rowbase - 4096; src = e2; woff = DDIM; dd = p2d; dg = p2g; ise2 = 1; }
    const float* e0 = src + (size_t)(r0 + grp * 4) * DDIM;
    const float* wdp = Wd + (size_t)woff * KDIM + kks;
    const float* wgp = Wg + (size_t)woff * KDIM + kks;

    float ad[4] = {0.f, 0.f, 0.f, 0.f}, ag[4] = {0.f, 0.f, 0.f, 0.f};
    for (int c = 0; c < DDIM / 4; ++c) {
        const int d0 = c * 4;
        float4 x[4];
#pragma unroll
        for (int rr = 0; rr < 4; ++rr)
            x[rr] = *(const float4*)(e0 + (size_t)rr * DDIM + d0);
        float wd0 = wdp[(size_t)(d0 + 0) * KDIM];
        float wd1 = wdp[(size_t)(d0 + 1) * KDIM];
        float wd2 = wdp[(size_t)(d0 + 2) * KDIM];
        float wd3 = wdp[(size_t)(d0 + 3) * KDIM];
        float wg0 = wgp[(size_t)(d0 + 0) * KDIM];
        float wg1 = wgp[(size_t)(d0 + 1) * KDIM];
        float wg2 = wgp[(size_t)(d0 + 2) * KDIM];
        float wg3 = wgp[(size_t)(d0 + 3) * KDIM];
#pragma unroll
        for (int rr = 0; rr < 4; ++rr) {
            ad[rr] += x[rr].x * wd0 + x[rr].y * wd1 + x[rr].z * wd2 + x[rr].w * wd3;
            ag[rr] += x[rr].x * wg0 + x[rr].y * wg1 + x[rr].z * wg2 + x[rr].w * wg3;
        }
    }
    if (kk < KDIM) {
#pragma unroll
        for (int rr = 0; rr < 4; ++rr) {
            size_t o = (size_t)(r0 + grp * 4 + rr) * KDIM + kk;
            dd[o] = ad[rr];
            dg[o] = ag[rr];
        }
    }
    // conversion: this block's 16 rows -> bf16 (640 granules of 8)
    for (int it = 0; it < 3; ++it) {
        int g = threadIdx.x + it * 256;
        if (g >= 640) break;
        int rl = g / 40, d0 = (g % 40) * 8;
        const float* sp = src + (size_t)(r0 + rl) * DDIM;
        float v[8];
        if (d0 + 8 <= DDIM) {
            float4 lo = *(const float4*)(sp + d0);
            float4 hi = *(const float4*)(sp + d0 + 4);
            v[0] = lo.x; v[1] = lo.y; v[2] = lo.z; v[3] = lo.w;
            v[4] = hi.x; v[5] = hi.y; v[6] = hi.z; v[7] = hi.w;
        } else if (d0 < DDIM) {          // d0 == 296
            float4 lo = *(const float4*)(sp + d0);
            v[0] = lo.x; v[1] = lo.y; v[2] = lo.z; v[3] = lo.w;
            v[4] = v[5] = v[6] = v[7] = 0.f;
        } else {
            for (int j = 0; j < 8; ++j) v[j] = 0.f;
        }
        unsigned short tmp[8];
#pragma unroll
        for (int j = 0; j < 8; ++j) tmp[j] = f2bf(v[j]);
        unsigned short* dp;
        int row = r0 + rl;
        if (!ise2) {
            dp = e1b + (size_t)row * DP + d0;                      // row-major padded
        } else {
            int bb2 = row >> 7, j = row & 127;
            int g8 = d0 >> 3, et = g8 >> 2, gg = g8 & 3;
            dp = e2til + (((size_t)(bb2 * 10 + et) * 4 + gg) * 128 + j) * 8;
        }
        *(short8*)dp = *(short8*)tmp;
    }
}

// ---------- main: per (b,k): S = (e1 Wb[k]) e2^T, gate ----------
// R6-exact (verified 94.5-96.5us across 5 runs): counted-vmcnt pipeline
// (T3/T4): wtile 3-deep (60KB), e2s 2-deep; iter n issues e2s(n+1) THEN
// wtile(n+2); barrier is raw s_barrier with s_waitcnt vmcnt(5) -- wtile(n+2)'s
// 5 loads stay in flight across it. No setprio (R8: T5 null on this
// barrier-lockstep structure). R9 lesson: do NOT remove the LDS stage -- it
// IS the latency-hiding mechanism (direct-global fragments = 2x slower).
template <int SLAB>
__global__ __launch_bounds__(256, 2) void grn_main(
    const unsigned short* __restrict__ e1b, const unsigned short* __restrict__ e2til,
    const unsigned short* __restrict__ wbt,
    const float* __restrict__ p1d, const float* __restrict__ p1g,
    const float* __restrict__ p2d, const float* __restrict__ p2g,
    const float* __restrict__ bg, const float* __restrict__ bb,
    const float* __restrict__ u, float* __restrict__ out, _Float16* __restrict__ slab) {
    const int b = blockIdx.x, k = blockIdx.y;
    const int tid = threadIdx.x;
    const int wid = tid >> 6, lane = tid & 63;
    const int l32 = lane & 31, hi = lane >> 5;
    const int rw0 = wid * 32;                      // wave owns i-rows [rw0, rw0+32)

    __shared__ __align__(16) unsigned short wtile[3][WTILE_E];   // 3 x 20480B
    __shared__ __align__(16) unsigned short e2s[2][E2TILE_E];    // 2 x 8192B
    __shared__ float pbuf[4][128];

    const unsigned short* wsrc = wbt + (size_t)k * WBT_K;
    const unsigned short* esrc = e2til + (size_t)b * (10 * E2TILE_E);

    // prologue stage: e2s(0), wtile(0) first (oldest -> drained by vmcnt(5))
#pragma unroll
    for (int it = 0; it < 2; ++it) {
        int c = wid * 2 + it;
        gload_lds16(esrc + c * 512 + lane * 8, &e2s[0][c * 512]);
    }
#pragma unroll
    for (int it = 0; it < 5; ++it) {
        int c = wid * 5 + it;
        gload_lds16(wsrc + c * 512 + lane * 8, &wtile[0][c * 512]);
    }

    if (tid < 128) {
        int gi = (b * LL + tid) * KDIM + k;
        pbuf[0][tid] = p1d[gi];
        pbuf[1][tid] = p1g[gi];
        pbuf[2][tid] = p2d[gi];
        pbuf[3][tid] = p2g[gi];
    }
    const float u_k = u[k], bg_k = bg[k], b_k = bb[k];

    // e1 B-fragments (phase1): lane holds e1[i=rw0+l32][d=c*16+hi*8+j], c=0..19
    short8 af[20];
    {
        const unsigned short* p = e1b + ((size_t)(b * LL + rw0 + l32)) * DP + hi * 8;
#pragma unroll
        for (int c = 0; c < 20; ++c)
            af[c] = *(const short8*)(p + c * 16);
    }

    float16v S[4];
#pragma unroll
    for (int jt = 0; jt < 4; ++jt)
#pragma unroll
        for (int z = 0; z < 16; ++z) S[jt][z] = 0.f;

    const int swz = (l32 & 7) << 3;                 // phase1 read swizzle (elems)
    const int ebo = hi * 1024 + l32 * 8;            // e2s frag base (elems)

    // prologue stage: wtile(1) LAST (the 5 loads vmcnt(5) leaves in flight)
    __builtin_amdgcn_sched_barrier(0);
#pragma unroll
    for (int it = 0; it < 5; ++it) {
        int c = wid * 5 + it;
        gload_lds16(wsrc + WTILE_E + c * 512 + lane * 8, &wtile[1][c * 512]);
    }
    asm volatile("s_waitcnt vmcnt(5)" ::: "memory");
    __builtin_amdgcn_s_barrier();
    __builtin_amdgcn_sched_barrier(0);

#pragma unroll
    for (int et = 0; et < 10; ++et) {
        const int wr = et % 3;                     // literal (unrolled)
        const int er = et & 1;
        // ks0 B-frags from LDS (current slot)
        short8 b0[4];
#pragma unroll
        for (int jt = 0; jt < 4; ++jt)
            b0[jt] = *(const short8*)&e2s[er][ebo + jt * 256];

        // stage e2s(et+1) FIRST, then wtile(et+2): vmcnt(5) leaves only the
        // wtile(et+2) loads outstanding across the barrier.
        if (et < 9) {
            const unsigned short* es = esrc + (et + 1) * E2TILE_E;
            unsigned short* el = &e2s[er ^ 1][0];
#pragma unroll
            for (int it = 0; it < 2; ++it) {
                int c = wid * 2 + it;
                gload_lds16(es + c * 512 + lane * 8, el + c * 512);
            }
        }
        __builtin_amdgcn_sched_barrier(0);          // pin e2s-before-wtile order
        if (et < 8) {
            const unsigned short* ws = wsrc + (et + 2) * WTILE_E;
            unsigned short* wl = &wtile[(et + 2) % 3][0];
#pragma unroll
            for (int it = 0; it < 5; ++it) {
                int c = wid * 5 + it;
                gload_lds16(ws + c * 512 + lane * 8, wl + c * 512);
            }
        }

        // phase 1 (mfma32): C[m=e'][n=i] = sum_d Wb[e'][d]*e1[i][d]
        const unsigned short* wt = &wtile[wr][l32 * 320];
        float16v t0, t1;
#pragma unroll
        for (int z = 0; z < 16; ++z) { t0[z] = 0.f; t1[z] = 0.f; }
#pragma unroll
        for (int c = 0; c < 20; c += 2) {
            short8 wa0 = *(const short8*)(wt + ((c * 16 + hi * 8) ^ swz));
            short8 wa1 = *(const short8*)(wt + (((c + 1) * 16 + hi * 8) ^ swz));
            t0 = mfma32(wa0, af[c], t0);
            t1 = mfma32(wa1, af[c + 1], t1);
        }
        // ks1 B-frags (LDS; cover = pack/swap + ks0 MFMAs)
        short8 b1[4];
#pragma unroll
        for (int jt = 0; jt < 4; ++jt)
            b1[jt] = *(const short8*)&e2s[er][ebo + 2048 + jt * 256];

        float16v tt = t0 + t1;
        // pack to bf16 pairs; lane (l32,hi) holds T[i=l32][e'=(r&3)+8*(r>>2)+4*hi]
        unsigned int P0 = cvtpk(tt[0], tt[1]);
        unsigned int P1 = cvtpk(tt[2], tt[3]);
        unsigned int P2 = cvtpk(tt[4], tt[5]);
        unsigned int P3 = cvtpk(tt[6], tt[7]);
        unsigned int P4 = cvtpk(tt[8], tt[9]);
        unsigned int P5 = cvtpk(tt[10], tt[11]);
        unsigned int P6 = cvtpk(tt[12], tt[13]);
        unsigned int P7 = cvtpk(tt[14], tt[15]);
        // half-wave exchange: dst'={dst_lo,src_lo}, src'={dst_hi,src_hi}
        int2v r02 = __builtin_amdgcn_permlane32_swap((int)P0, (int)P2, false, false);
        int2v r13 = __builtin_amdgcn_permlane32_swap((int)P1, (int)P3, false, false);
        int2v r46 = __builtin_amdgcn_permlane32_swap((int)P4, (int)P6, false, false);
        int2v r57 = __builtin_amdgcn_permlane32_swap((int)P5, (int)P7, false, false);
        short8 A0 = __builtin_bit_cast(short8, (int4v){r02[0], r13[0], r02[1], r13[1]});
        short8 A1 = __builtin_bit_cast(short8, (int4v){r46[0], r57[0], r46[1], r57[1]});
        // phase 2 (mfma32): S[i][j] += sum_e' T[i][e'] * e2[j][e']
#pragma unroll
        for (int jt = 0; jt < 4; ++jt)
            S[jt] = mfma32(A0, b0[jt], S[jt]);
#pragma unroll
        for (int jt = 0; jt < 4; ++jt)
            S[jt] = mfma32(A1, b1[jt], S[jt]);

        // counted-vmcnt barrier: wtile(et+2) stays in flight (T4).
        if (et < 8) {
            asm volatile("s_waitcnt vmcnt(5)" ::: "memory");
        } else if (et == 8) {
            asm volatile("s_waitcnt vmcnt(0)" ::: "memory");
        }
        if (et < 9) {
            __builtin_amdgcn_s_barrier();
            __builtin_amdgcn_sched_barrier(0);
        }
    }

    // epilogue: gate, mix, scale by u[k]
    // S[jt][r]: i = rw0 + (r&3)+8*(r>>2)+4*hi, j = jt*32 + l32
    float pdj[4], pgj[4];
#pragma unroll
    for (int jt = 0; jt < 4; ++jt) {
        pdj[jt] = pbuf[2][jt * 32 + l32];
        pgj[jt] = pbuf[3][jt * 32 + l32] + bg_k;
    }
    _Float16* sdst = slab + ((size_t)k * NB + b) * 16384;
    float* adst = out + (size_t)b * LL * LL;
#pragma unroll
    for (int r = 0; r < 16; ++r) {
        int i = rw0 + (r & 3) + 8 * (r >> 2) + 4 * hi;
        float pdi_ = pbuf[0][i];
        float pgi_ = pbuf[1][i];
#pragma unroll
        for (int jt = 0; jt < 4; ++jt) {
            float btp = S[jt][r];
            float sd = pdi_ + pdj[jt];
            float sg = pgi_ + pgj[jt];
            float e2x = __expf(2.f * sd);
            float sln = 1.f - 2.f * __builtin_amdgcn_rcpf(e2x + 1.f);   // tanh(sd)
            float g = __builtin_amdgcn_rcpf(1.f + __expf(-sg));          // sigmoid(sg)
            float val = u_k * (g * btp + (1.f - g) * sln + b_k);
            if (SLAB) {
                // permuted coalesced layout: pos = v*256 + tid, v = jt*16 + r
                sdst[(jt * 16 + r) * 256 + tid] = (_Float16)val;
            } else {
                unsafeAtomicAdd(adst + (size_t)i * LL + (jt * 32 + l32), val);
            }
        }
    }
}

// ---------- reduce: out[b][i][j] = sum_k slab[k][b][pos]; decode permutation ----------
__global__ void reduce_k(const _Float16* __restrict__ slab, float* __restrict__ out) {
    int idx = blockIdx.x * 256 + threadIdx.x;     // 0..131071
    int b = idx >> 12;
    int p4 = idx & 4095;
    int pos0 = p4 * 4;
    int v = pos0 >> 8, tid0 = pos0 & 255;
    int jt = v >> 4, r = v & 15;
    int wid = tid0 >> 6, lane = tid0 & 63, hi2 = lane >> 5, l32 = lane & 31;
    int i = wid * 32 + (r & 3) + 8 * (r >> 2) + 4 * hi2;
    int j0 = jt * 32 + l32;

    float a0 = 0.f, a1 = 0.f, a2 = 0.f, a3 = 0.f;
    const _Float16* sp = slab + (size_t)b * 16384 + pos0;
#pragma unroll
    for (int k = 0; k < KDIM; ++k) {
        half4v h = *(const half4v*)(sp + (size_t)k * (NB * 16384));
        a0 += (float)h[0]; a1 += (float)h[1]; a2 += (float)h[2]; a3 += (float)h[3];
    }
    float4 rv; rv.x = a0; rv.y = a1; rv.z = a2; rv.w = a3;
    *(float4*)(out + (size_t)b * 16384 + i * 128 + j0) = rv;
}

extern "C" void kernel_launch(void* const* d_in, const int* in_sizes, int n_in,
                              void* d_out, int out_size, void* d_ws, size_t ws_size,
                              hipStream_t stream) {
    const float* e1 = (const float*)d_in[0];   // (32,128,300)
    const float* e2 = (const float*)d_in[1];   // (32,128,300)
    const float* Wb = (const float*)d_in[2];   // (50,300,300)
    const float* Wd = (const float*)d_in[3];   // (600,50)
    const float* Wg = (const float*)d_in[4];   // (600,50)
    const float* bg = (const float*)d_in[5];   // (50,)
    const float* bb = (const float*)d_in[6];   // (50,)
    const float* u  = (const float*)d_in[7];   // (50,1)
    float* out = (float*)d_out;                // (32,128,128,1)

    unsigned short* e1b   = (unsigned short*)d_ws;               // 1,310,720 elems
    unsigned short* e2til = e1b + 1310720;                       // 1,310,720 elems (tiled)
    unsigned short* wbt   = e2til + 1310720;                     // 5,120,000 elems
    float* pf  = (float*)((char*)d_ws + 15482880);
    float* p1d = pf;
    float* p1g = pf + 204800;
    float* p2d = pf + 409600;
    float* p2g = pf + 614400;                                    // end 18,759,680 B
    _Float16* slab = (_Float16*)((char*)d_ws + SLAB_OFF);        // 50x32x16384 halves

    prep_all<<<1512, 256, 0, stream>>>(e1, e2, Wb, Wd, Wg,
                                       e1b, e2til, wbt,
                                       p1d, p1g, p2d, p2g);

    if (ws_size >= WS_NEED) {
        grn_main<1><<<dim3(NB, KDIM), 256, 0, stream>>>(e1b, e2til, wbt,
                                                        p1d, p1g, p2d, p2g,
                                                        bg, bb, u, out, slab);
        reduce_k<<<512, 256, 0, stream>>>(slab, out);
    } else {
        hipMemsetAsync(d_out, 0, (size_t)out_size * sizeof(float), stream);
        grn_main<0><<<dim3(NB, KDIM), 256, 0, stream>>>(e1b, e2til, wbt,
                                                        p1d, p1g, p2d, p2g,
                                                        bg, bb, u, out, slab);
    }
}

// Round 17
// 208.174 us; speedup vs baseline: 1.0445x; 1.0401x over previous
//
#include <hip/hip_runtime.h>
#include <hip/hip_bf16.h>

typedef __attribute__((ext_vector_type(8))) short short8;
typedef __attribute__((ext_vector_type(16))) float float16v;
typedef __attribute__((ext_vector_type(4))) int int4v;
typedef __attribute__((ext_vector_type(2))) int int2v;
typedef _Float16 half4v __attribute__((ext_vector_type(4)));

#define NB 32
#define LL 128
#define DDIM 300
#define DP 320
#define KDIM 50
#define WTILE_E 10240            // elems per (k, et) wtile: 32 rows x 320
#define WBT_K   102400           // elems per k (10 tiles)
#define E2TILE_E 4096            // elems per (b, et) e2 tile: 4 granules x 128 j x 8
#define SLAB_OFF 18759680ull
#define SLAB_BYTES (50ull * 32ull * 16384ull * 2ull)          // 52,428,800
#define WS_NEED  (SLAB_OFF + SLAB_BYTES)

__device__ __forceinline__ unsigned short f2bf(float x) {
    unsigned int u = __float_as_uint(x);
    unsigned int r = (u + 0x7FFFu + ((u >> 16) & 1u)) >> 16;
    return (unsigned short)r;
}
__device__ __forceinline__ float16v mfma32(short8 a, short8 b, float16v c) {
    return __builtin_amdgcn_mfma_f32_32x32x16_bf16(a, b, c, 0, 0, 0);
}
__device__ __forceinline__ unsigned int cvtpk(float lo, float hi) {
    unsigned int r;
    asm("v_cvt_pk_bf16_f32 %0, %1, %2" : "=v"(r) : "v"(lo), "v"(hi));
    return r;
}
__device__ __forceinline__ void gload_lds16(const void* g, void* l) {
    __builtin_amdgcn_global_load_lds((const __attribute__((address_space(1))) void*)g,
                                     (__attribute__((address_space(3))) void*)l, 16, 0, 0);
}

// ---------- fused prep: [0,1000) Wb->Wbt arm; [1000,1512) projections+convert arm ----------
// FINAL = R6-exact. Arm order transpose-first/projection-last is deliberate:
// R15 proved grn's duration depends on prep-exit L2 state -- projection last
// leaves e1b/e2til/p* (grn's prologue + e2s reads) L2-warm; swapping saved
// prep ~20us but cost grn +20us (zero-sum via cache).
// Wbt layout (XOR-swizzled for grn's global_load_lds staging):
//   elem offset = k*102400 + et*10240 + (e&31)*320 + (d ^ ((e&7)<<3))
// Transpose arm: writer gathers 8 consecutive d down an LDS column
// (stride-33, conflict-free) and emits ONE short8 store. 1000 blocks.
// e2til layout: per (b, et) linear 8192B tile, granule-major:
//   elem ((b*10+et)*4 + g)*1024 + j*8 + jj
__global__ void prep_all(const float* __restrict__ e1, const float* __restrict__ e2,
                         const float* __restrict__ Wb,
                         const float* __restrict__ Wd, const float* __restrict__ Wg,
                         unsigned short* __restrict__ e1b, unsigned short* __restrict__ e2til,
                         unsigned short* __restrict__ wbt,
                         float* __restrict__ p1d, float* __restrict__ p1g,
                         float* __restrict__ p2d, float* __restrict__ p2g) {
    const int blk = blockIdx.x;
    __shared__ float tile[32][33];

    if (blk < 1000) {
        // ---- Wb transpose arm: (k, et, dt-half); 5 dt rounds ----
        int k = blk / 20, sub = blk % 20, et = sub >> 1, dh = sub & 1;
        int tx = threadIdx.x & 31, ty = threadIdx.x >> 5;
        const size_t obase = (size_t)k * WBT_K + (size_t)et * WTILE_E;
        for (int dt = dh * 5; dt < dh * 5 + 5; ++dt) {
#pragma unroll
            for (int rr = 0; rr < 4; ++rr) {
                int d = dt * 32 + ty + rr * 8;
                int e = et * 32 + tx;
                tile[ty + rr * 8][tx] = (d < DDIM && e < DDIM) ? Wb[((size_t)k * DDIM + d) * DDIM + e] : 0.f;
            }
            __syncthreads();
            if (threadIdx.x < 128) {
                int e_loc = threadIdx.x & 31, oct = threadIdx.x >> 5;   // oct 0..3
                int e7 = e_loc & 7;
                unsigned short tmp[8];
#pragma unroll
                for (int s = 0; s < 8; ++s)
                    tmp[s] = f2bf(tile[oct * 8 + s][e_loc]);
                int d0g = dt * 32 + oct * 8;
                size_t off = obase + (size_t)e_loc * 320 + (size_t)(d0g ^ (e7 << 3));
                *(short8*)&wbt[off] = *(short8*)tmp;
            }
            __syncthreads();
        }
        return;
    }
    // ---- projection + conversion arm: 512 blocks, 16 rows each ----
    int bid = blk - 1000;
    const int kk = threadIdx.x & 63;
    const int grp = threadIdx.x >> 6;
    const int kks = kk < KDIM ? kk : 0;
    const float* src; int woff; float *dd, *dg; int r0;
    int ise2;
    int rowbase = bid * 16;
    if (rowbase < 4096) { r0 = rowbase; src = e1; woff = 0; dd = p1d; dg = p1g; ise2 = 0; }
    else { r0 = rowbase - 4096; src = e2; woff = DDIM; dd = p2d; dg = p2g; ise2 = 1; }
    const float* e0 = src + (size_t)(r0 + grp * 4) * DDIM;
    const float* wdp = Wd + (size_t)woff * KDIM + kks;
    const float* wgp = Wg + (size_t)woff * KDIM + kks;

    float ad[4] = {0.f, 0.f, 0.f, 0.f}, ag[4] = {0.f, 0.f, 0.f, 0.f};
    for (int c = 0; c < DDIM / 4; ++c) {
        const int d0 = c * 4;
        float4 x[4];
#pragma unroll
        for (int rr = 0; rr < 4; ++rr)
            x[rr] = *(const float4*)(e0 + (size_t)rr * DDIM + d0);
        float wd0 = wdp[(size_t)(d0 + 0) * KDIM];
        float wd1 = wdp[(size_t)(d0 + 1) * KDIM];
        float wd2 = wdp[(size_t)(d0 + 2) * KDIM];
        float wd3 = wdp[(size_t)(d0 + 3) * KDIM];
        float wg0 = wgp[(size_t)(d0 + 0) * KDIM];
        float wg1 = wgp[(size_t)(d0 + 1) * KDIM];
        float wg2 = wgp[(size_t)(d0 + 2) * KDIM];
        float wg3 = wgp[(size_t)(d0 + 3) * KDIM];
#pragma unroll
        for (int rr = 0; rr < 4; ++rr) {
            ad[rr] += x[rr].x * wd0 + x[rr].y * wd1 + x[rr].z * wd2 + x[rr].w * wd3;
            ag[rr] += x[rr].x * wg0 + x[rr].y * wg1 + x[rr].z * wg2 + x[rr].w * wg3;
        }
    }
    if (kk < KDIM) {
#pragma unroll
        for (int rr = 0; rr < 4; ++rr) {
            size_t o = (size_t)(r0 + grp * 4 + rr) * KDIM + kk;
            dd[o] = ad[rr];
            dg[o] = ag[rr];
        }
    }
    // conversion: this block's 16 rows -> bf16 (640 granules of 8)
    for (int it = 0; it < 3; ++it) {
        int g = threadIdx.x + it * 256;
        if (g >= 640) break;
        int rl = g / 40, d0 = (g % 40) * 8;
        const float* sp = src + (size_t)(r0 + rl) * DDIM;
        float v[8];
        if (d0 + 8 <= DDIM) {
            float4 lo = *(const float4*)(sp + d0);
            float4 hi = *(const float4*)(sp + d0 + 4);
            v[0] = lo.x; v[1] = lo.y; v[2] = lo.z; v[3] = lo.w;
            v[4] = hi.x; v[5] = hi.y; v[6] = hi.z; v[7] = hi.w;
        } else if (d0 < DDIM) {          // d0 == 296
            float4 lo = *(const float4*)(sp + d0);
            v[0] = lo.x; v[1] = lo.y; v[2] = lo.z; v[3] = lo.w;
            v[4] = v[5] = v[6] = v[7] = 0.f;
        } else {
            for (int j = 0; j < 8; ++j) v[j] = 0.f;
        }
        unsigned short tmp[8];
#pragma unroll
        for (int j = 0; j < 8; ++j) tmp[j] = f2bf(v[j]);
        unsigned short* dp;
        int row = r0 + rl;
        if (!ise2) {
            dp = e1b + (size_t)row * DP + d0;                      // row-major padded
        } else {
            int bb2 = row >> 7, j = row & 127;
            int g8 = d0 >> 3, et = g8 >> 2, gg = g8 & 3;
            dp = e2til + (((size_t)(bb2 * 10 + et) * 4 + gg) * 128 + j) * 8;
        }
        *(short8*)dp = *(short8*)tmp;
    }
}

// ---------- main: per (b,k): S = (e1 Wb[k]) e2^T, gate ----------
// R6-exact (verified 94.5-96.5us across 5 runs): counted-vmcnt pipeline
// (T3/T4): wtile 3-deep (60KB), e2s 2-deep; iter n issues e2s(n+1) THEN
// wtile(n+2); barrier is raw s_barrier with s_waitcnt vmcnt(5) -- wtile(n+2)'s
// 5 loads stay in flight across it. No setprio (R8: T5 null on this
// barrier-lockstep structure). R9 lesson: do NOT remove the LDS stage -- it
// IS the latency-hiding mechanism (direct-global fragments = 2x slower).
template <int SLAB>
__global__ __launch_bounds__(256, 2) void grn_main(
    const unsigned short* __restrict__ e1b, const unsigned short* __restrict__ e2til,
    const unsigned short* __restrict__ wbt,
    const float* __restrict__ p1d, const float* __restrict__ p1g,
    const float* __restrict__ p2d, const float* __restrict__ p2g,
    const float* __restrict__ bg, const float* __restrict__ bb,
    const float* __restrict__ u, float* __restrict__ out, _Float16* __restrict__ slab) {
    const int b = blockIdx.x, k = blockIdx.y;
    const int tid = threadIdx.x;
    const int wid = tid >> 6, lane = tid & 63;
    const int l32 = lane & 31, hi = lane >> 5;
    const int rw0 = wid * 32;                      // wave owns i-rows [rw0, rw0+32)

    __shared__ __align__(16) unsigned short wtile[3][WTILE_E];   // 3 x 20480B
    __shared__ __align__(16) unsigned short e2s[2][E2TILE_E];    // 2 x 8192B
    __shared__ float pbuf[4][128];

    const unsigned short* wsrc = wbt + (size_t)k * WBT_K;
    const unsigned short* esrc = e2til + (size_t)b * (10 * E2TILE_E);

    // prologue stage: e2s(0), wtile(0) first (oldest -> drained by vmcnt(5))
#pragma unroll
    for (int it = 0; it < 2; ++it) {
        int c = wid * 2 + it;
        gload_lds16(esrc + c * 512 + lane * 8, &e2s[0][c * 512]);
    }
#pragma unroll
    for (int it = 0; it < 5; ++it) {
        int c = wid * 5 + it;
        gload_lds16(wsrc + c * 512 + lane * 8, &wtile[0][c * 512]);
    }

    if (tid < 128) {
        int gi = (b * LL + tid) * KDIM + k;
        pbuf[0][tid] = p1d[gi];
        pbuf[1][tid] = p1g[gi];
        pbuf[2][tid] = p2d[gi];
        pbuf[3][tid] = p2g[gi];
    }
    const float u_k = u[k], bg_k = bg[k], b_k = bb[k];

    // e1 B-fragments (phase1): lane holds e1[i=rw0+l32][d=c*16+hi*8+j], c=0..19
    short8 af[20];
    {
        const unsigned short* p = e1b + ((size_t)(b * LL + rw0 + l32)) * DP + hi * 8;
#pragma unroll
        for (int c = 0; c < 20; ++c)
            af[c] = *(const short8*)(p + c * 16);
    }

    float16v S[4];
#pragma unroll
    for (int jt = 0; jt < 4; ++jt)
#pragma unroll
        for (int z = 0; z < 16; ++z) S[jt][z] = 0.f;

    const int swz = (l32 & 7) << 3;                 // phase1 read swizzle (elems)
    const int ebo = hi * 1024 + l32 * 8;            // e2s frag base (elems)

    // prologue stage: wtile(1) LAST (the 5 loads vmcnt(5) leaves in flight)
    __builtin_amdgcn_sched_barrier(0);
#pragma unroll
    for (int it = 0; it < 5; ++it) {
        int c = wid * 5 + it;
        gload_lds16(wsrc + WTILE_E + c * 512 + lane * 8, &wtile[1][c * 512]);
    }
    asm volatile("s_waitcnt vmcnt(5)" ::: "memory");
    __builtin_amdgcn_s_barrier();
    __builtin_amdgcn_sched_barrier(0);

#pragma unroll
    for (int et = 0; et < 10; ++et) {
        const int wr = et % 3;                     // literal (unrolled)
        const int er = et & 1;
        // ks0 B-frags from LDS (current slot)
        short8 b0[4];
#pragma unroll
        for (int jt = 0; jt < 4; ++jt)
            b0[jt] = *(const short8*)&e2s[er][ebo + jt * 256];

        // stage e2s(et+1) FIRST, then wtile(et+2): vmcnt(5) leaves only the
        // wtile(et+2) loads outstanding across the barrier.
        if (et < 9) {
            const unsigned short* es = esrc + (et + 1) * E2TILE_E;
            unsigned short* el = &e2s[er ^ 1][0];
#pragma unroll
            for (int it = 0; it < 2; ++it) {
                int c = wid * 2 + it;
                gload_lds16(es + c * 512 + lane * 8, el + c * 512);
            }
        }
        __builtin_amdgcn_sched_barrier(0);          // pin e2s-before-wtile order
        if (et < 8) {
            const unsigned short* ws = wsrc + (et + 2) * WTILE_E;
            unsigned short* wl = &wtile[(et + 2) % 3][0];
#pragma unroll
            for (int it = 0; it < 5; ++it) {
                int c = wid * 5 + it;
                gload_lds16(ws + c * 512 + lane * 8, wl + c * 512);
            }
        }

        // phase 1 (mfma32): C[m=e'][n=i] = sum_d Wb[e'][d]*e1[i][d]
        const unsigned short* wt = &wtile[wr][l32 * 320];
        float16v t0, t1;
#pragma unroll
        for (int z = 0; z < 16; ++z) { t0[z] = 0.f; t1[z] = 0.f; }
#pragma unroll
        for (int c = 0; c < 20; c += 2) {
            short8 wa0 = *(const short8*)(wt + ((c * 16 + hi * 8) ^ swz));
            short8 wa1 = *(const short8*)(wt + (((c + 1) * 16 + hi * 8) ^ swz));
            t0 = mfma32(wa0, af[c], t0);
            t1 = mfma32(wa1, af[c + 1], t1);
        }
        // ks1 B-frags (LDS; cover = pack/swap + ks0 MFMAs)
        short8 b1[4];
#pragma unroll
        for (int jt = 0; jt < 4; ++jt)
            b1[jt] = *(const short8*)&e2s[er][ebo + 2048 + jt * 256];

        float16v tt = t0 + t1;
        // pack to bf16 pairs; lane (l32,hi) holds T[i=l32][e'=(r&3)+8*(r>>2)+4*hi]
        unsigned int P0 = cvtpk(tt[0], tt[1]);
        unsigned int P1 = cvtpk(tt[2], tt[3]);
        unsigned int P2 = cvtpk(tt[4], tt[5]);
        unsigned int P3 = cvtpk(tt[6], tt[7]);
        unsigned int P4 = cvtpk(tt[8], tt[9]);
        unsigned int P5 = cvtpk(tt[10], tt[11]);
        unsigned int P6 = cvtpk(tt[12], tt[13]);
        unsigned int P7 = cvtpk(tt[14], tt[15]);
        // half-wave exchange: dst'={dst_lo,src_lo}, src'={dst_hi,src_hi}
        int2v r02 = __builtin_amdgcn_permlane32_swap((int)P0, (int)P2, false, false);
        int2v r13 = __builtin_amdgcn_permlane32_swap((int)P1, (int)P3, false, false);
        int2v r46 = __builtin_amdgcn_permlane32_swap((int)P4, (int)P6, false, false);
        int2v r57 = __builtin_amdgcn_permlane32_swap((int)P5, (int)P7, false, false);
        short8 A0 = __builtin_bit_cast(short8, (int4v){r02[0], r13[0], r02[1], r13[1]});
        short8 A1 = __builtin_bit_cast(short8, (int4v){r46[0], r57[0], r46[1], r57[1]});
        // phase 2 (mfma32): S[i][j] += sum_e' T[i][e'] * e2[j][e']
#pragma unroll
        for (int jt = 0; jt < 4; ++jt)
            S[jt] = mfma32(A0, b0[jt], S[jt]);
#pragma unroll
        for (int jt = 0; jt < 4; ++jt)
            S[jt] = mfma32(A1, b1[jt], S[jt]);

        // counted-vmcnt barrier: wtile(et+2) stays in flight (T4).
        if (et < 8) {
            asm volatile("s_waitcnt vmcnt(5)" ::: "memory");
        } else if (et == 8) {
            asm volatile("s_waitcnt vmcnt(0)" ::: "memory");
        }
        if (et < 9) {
            __builtin_amdgcn_s_barrier();
            __builtin_amdgcn_sched_barrier(0);
        }
    }

    // epilogue: gate, mix, scale by u[k]
    // S[jt][r]: i = rw0 + (r&3)+8*(r>>2)+4*hi, j = jt*32 + l32
    float pdj[4], pgj[4];
#pragma unroll
    for (int jt = 0; jt < 4; ++jt) {
        pdj[jt] = pbuf[2][jt * 32 + l32];
        pgj[jt] = pbuf[3][jt * 32 + l32] + bg_k;
    }
    _Float16* sdst = slab + ((size_t)k * NB + b) * 16384;
    float* adst = out + (size_t)b * LL * LL;
#pragma unroll
    for (int r = 0; r < 16; ++r) {
        int i = rw0 + (r & 3) + 8 * (r >> 2) + 4 * hi;
        float pdi_ = pbuf[0][i];
        float pgi_ = pbuf[1][i];
#pragma unroll
        for (int jt = 0; jt < 4; ++jt) {
            float btp = S[jt][r];
            float sd = pdi_ + pdj[jt];
            float sg = pgi_ + pgj[jt];
            float e2x = __expf(2.f * sd);
            float sln = 1.f - 2.f * __builtin_amdgcn_rcpf(e2x + 1.f);   // tanh(sd)
            float g = __builtin_amdgcn_rcpf(1.f + __expf(-sg));          // sigmoid(sg)
            float val = u_k * (g * btp + (1.f - g) * sln + b_k);
            if (SLAB) {
                // permuted coalesced layout: pos = v*256 + tid, v = jt*16 + r
                sdst[(jt * 16 + r) * 256 + tid] = (_Float16)val;
            } else {
                unsafeAtomicAdd(adst + (size_t)i * LL + (jt * 32 + l32), val);
            }
        }
    }
}

// ---------- reduce: out[b][i][j] = sum_k slab[k][b][pos]; decode permutation ----------
__global__ void reduce_k(const _Float16* __restrict__ slab, float* __restrict__ out) {
    int idx = blockIdx.x * 256 + threadIdx.x;     // 0..131071
    int b = idx >> 12;
    int p4 = idx & 4095;
    int pos0 = p4 * 4;
    int v = pos0 >> 8, tid0 = pos0 & 255;
    int jt = v >> 4, r = v & 15;
    int wid = tid0 >> 6, lane = tid0 & 63, hi2 = lane >> 5, l32 = lane & 31;
    int i = wid * 32 + (r & 3) + 8 * (r >> 2) + 4 * hi2;
    int j0 = jt * 32 + l32;

    float a0 = 0.f, a1 = 0.f, a2 = 0.f, a3 = 0.f;
    const _Float16* sp = slab + (size_t)b * 16384 + pos0;
#pragma unroll
    for (int k = 0; k < KDIM; ++k) {
        half4v h = *(const half4v*)(sp + (size_t)k * (NB * 16384));
        a0 += (float)h[0]; a1 += (float)h[1]; a2 += (float)h[2]; a3 += (float)h[3];
    }
    float4 rv; rv.x = a0; rv.y = a1; rv.z = a2; rv.w = a3;
    *(float4*)(out + (size_t)b * 16384 + i * 128 + j0) = rv;
}

extern "C" void kernel_launch(void* const* d_in, const int* in_sizes, int n_in,
                              void* d_out, int out_size, void* d_ws, size_t ws_size,
                              hipStream_t stream) {
    const float* e1 = (const float*)d_in[0];   // (32,128,300)
    const float* e2 = (const float*)d_in[1];   // (32,128,300)
    const float* Wb = (const float*)d_in[2];   // (50,300,300)
    const float* Wd = (const float*)d_in[3];   // (600,50)
    const float* Wg = (const float*)d_in[4];   // (600,50)
    const float* bg = (const float*)d_in[5];   // (50,)
    const float* bb = (const float*)d_in[6];   // (50,)
    const float* u  = (const float*)d_in[7];   // (50,1)
    float* out = (float*)d_out;                // (32,128,128,1)

    unsigned short* e1b   = (unsigned short*)d_ws;               // 1,310,720 elems
    unsigned short* e2til = e1b + 1310720;                       // 1,310,720 elems (tiled)
    unsigned short* wbt   = e2til + 1310720;                     // 5,120,000 elems
    float* pf  = (float*)((char*)d_ws + 15482880);
    float* p1d = pf;
    float* p1g = pf + 204800;
    float* p2d = pf + 409600;
    float* p2g = pf + 614400;                                    // end 18,759,680 B
    _Float16* slab = (_Float16*)((char*)d_ws + SLAB_OFF);        // 50x32x16384 halves

    prep_all<<<1512, 256, 0, stream>>>(e1, e2, Wb, Wd, Wg,
                                       e1b, e2til, wbt,
                                       p1d, p1g, p2d, p2g);

    if (ws_size >= WS_NEED) {
        grn_main<1><<<dim3(NB, KDIM), 256, 0, stream>>>(e1b, e2til, wbt,
                                                        p1d, p1g, p2d, p2g,
                                                        bg, bb, u, out, slab);
        reduce_k<<<512, 256, 0, stream>>>(slab, out);
    } else {
        hipMemsetAsync(d_out, 0, (size_t)out_size * sizeof(float), stream);
        grn_main<0><<<dim3(NB, KDIM), 256, 0, stream>>>(e1b, e2til, wbt,
                                                        p1d, p1g, p2d, p2g,
                                                        bg, bb, u, out, slab);
    }
}